// Round 1
// baseline (107.208 us; speedup 1.0000x reference)
//
#include <hip/hip_runtime.h>
#include <math.h>

// GlobalMatch: subsample stride-4 -> per batch 4096 pts x 256 ch,
// all-pairs min distance (a vs b), score = 2*sigmoid(-sqrt(d2min)), 4x4 upsample.
//
// Pipeline: gather/compact(fp16, K-chunked layout) -> fp16 MFMA GEMM with fused
// min-reduction -> finalize(score + upsample).

#define BATCH 4
#define CH    256
#define HH    256
#define WW    256
#define NSUB  64            // 256/4
#define NPTS  4096          // 64*64
#define EPSV  1e-6f

typedef _Float16 half8 __attribute__((ext_vector_type(8)));
typedef float    f32x4 __attribute__((ext_vector_type(4)));

typedef __attribute__((address_space(1))) const void global_cvoid;
typedef __attribute__((address_space(3))) void lds_void;

// ws layout (bytes)
#define AC_OFF   0u                          // fp16 chunks [b][kc(32)][n(4096)] * 16B = 8MB
#define BC_OFF   (8u << 20)                  // same, 8MB
#define A2_OFF   (16u << 20)                 // f32 [b][n]  a2 + 2eps*sa            (64KB)
#define B2_OFF   ((16u << 20) + (64u << 10)) // f32 [b][n]  b2 - 2eps*sb + C*eps^2  (64KB)
#define DP_OFF   ((16u << 20) + (128u << 10))// f32 [b][n][2] per-half min d2       (128KB)
#define WS_TOTAL ((16u << 20) + (256u << 10))

// ---------------------------------------------------------------- gather
// grid (64 h, 4 b, 2 input), block 256.
// Block covers one (input, b, h): all 64 w, all 256 c.
// thread t: w = t&63, wave wv = t>>6 covers c in [wv*64, wv*64+64).
__global__ __launch_bounds__(256) void gm_gather(
    const float* __restrict__ srcA, const float* __restrict__ srcB,
    unsigned char* __restrict__ ws)
{
  const int t  = threadIdx.x;
  const int h  = blockIdx.x;
  const int b  = blockIdx.y;
  const int z  = blockIdx.z;               // 0 -> a, 1 -> b
  const int w  = t & 63;
  const int wv = t >> 6;

  const float* src = z ? srcB : srcA;
  unsigned char* dst = ws + (z ? BC_OFF : AC_OFF);
  float* norms = (float*)(ws + (z ? B2_OFF : A2_OFF));
  const float epsSign = z ? -2.0f * EPSV : 2.0f * EPSV;
  const float addC    = z ? (float)CH * EPSV * EPSV : 0.0f;

  const float* rowbase = src + ((size_t)b * CH) * (HH * WW)
                             + (size_t)(h * 4) * WW + (size_t)(w * 4);
  float ssum = 0.0f, ssq = 0.0f;
  #pragma unroll
  for (int i = 0; i < 8; ++i) {
    const int kc = wv * 8 + i;             // 16B chunk index (8 channels)
    half8 hv;
    #pragma unroll
    for (int j = 0; j < 8; ++j) {
      const int c = kc * 8 + j;
      float v = rowbase[(size_t)c * (HH * WW)];
      ssum += v;
      ssq  = fmaf(v, v, ssq);
      hv[j] = (_Float16)v;
    }
    // chunk layout: [b][kc][n], n = h*64+w  -> lanes write contiguous 1KB
    *reinterpret_cast<half8*>(dst + ((size_t)((b * 32 + kc) * NPTS + h * 64 + w)) * 16) = hv;
  }

  __shared__ float red[2][4][64];
  red[0][wv][w] = ssum;
  red[1][wv][w] = ssq;
  __syncthreads();
  if (t < 64) {
    float sm = red[0][0][t] + red[0][1][t] + red[0][2][t] + red[0][3][t];
    float sq = red[1][0][t] + red[1][1][t] + red[1][2][t] + red[1][3][t];
    norms[b * NPTS + h * 64 + t] = fmaf(epsSign, sm, sq) + addC;
  }
}

// ---------------------------------------------------------------- gemm + min
// grid (2 m-half, 64 n-strip, 4 b), block 256 (4 waves).
// Block: 64 n rows x 2048 m cols, K=256. A tile 32KB staged once, B tile 32KB
// per 64-m step. Wave wv owns n rows [wv*16, wv*16+16). XOR swizzle
// byte ^= ((row&7)<<4) applied on the global_load_lds SOURCE and on ds_read.
__global__ __launch_bounds__(256, 2) void gm_gemm_min(
    const unsigned char* __restrict__ Ac, const unsigned char* __restrict__ Bc,
    const float* __restrict__ a2p, const float* __restrict__ b2pc,
    float* __restrict__ d2part)
{
  __shared__ __align__(16) unsigned char smem[65536];
  unsigned char* sA = smem;
  unsigned char* sB = smem + 32768;

  const int t  = threadIdx.x;
  const int mh = blockIdx.x;
  const int ns = blockIdx.y;
  const int b  = blockIdx.z;
  const int l  = t & 63;
  const int wv = t >> 6;
  const int nbase = ns * 64;

  // ---- stage A strip (64 rows x 256 K fp16 = 32KB), swizzled source
  #pragma unroll
  for (int r = 0; r < 8; ++r) {
    unsigned x  = (unsigned)(r * 256 + t) * 16;            // linear LDS dest byte
    unsigned lb = x ^ (((x >> 9) & 7) << 4);               // logical byte
    unsigned n_l = lb >> 9;
    unsigned kcb = (lb & 511) >> 4;
    const unsigned char* srcp =
        Ac + ((size_t)((b * 32 + kcb) * NPTS + nbase + n_l)) * 16;
    __builtin_amdgcn_global_load_lds((global_cvoid*)srcp,
                                     (lds_void*)(sA + (r * 4096 + wv * 1024)),
                                     16, 0, 0);
  }

  // a2p for this lane's 4 output rows: n = nbase + wv*16 + (l>>4)*4 + r
  const int rowg = nbase + wv * 16 + ((l >> 4) & 3) * 4;
  float a2pr[4];
  #pragma unroll
  for (int r = 0; r < 4; ++r) a2pr[r] = a2p[b * NPTS + rowg + r];

  asm volatile("s_waitcnt vmcnt(0)" ::: "memory");
  __syncthreads();

  // ---- A fragments for the whole K (8 k-steps), kept in registers
  half8 af[8];
  {
    const unsigned row  = wv * 16 + (l & 15);
    const unsigned base = row * 512 + ((l >> 4) & 3) * 16;
    const unsigned sw   = (row & 7) << 4;
    #pragma unroll
    for (int kk = 0; kk < 8; ++kk)
      af[kk] = *reinterpret_cast<const half8*>(sA + ((base + kk * 64) ^ sw));
  }

  float rmin[4][4];
  #pragma unroll
  for (int ms = 0; ms < 4; ++ms)
    #pragma unroll
    for (int r = 0; r < 4; ++r) rmin[ms][r] = 3.0e38f;

  const int mstart = mh * 2048;
  for (int mt = 0; mt < 32; ++mt) {
    const int mbase = mstart + mt * 64;

    // stage B tile (64 m rows x 256 K = 32KB)
    #pragma unroll
    for (int r = 0; r < 8; ++r) {
      unsigned x  = (unsigned)(r * 256 + t) * 16;
      unsigned lb = x ^ (((x >> 9) & 7) << 4);
      unsigned m_l = lb >> 9;
      unsigned kcb = (lb & 511) >> 4;
      const unsigned char* srcp =
          Bc + ((size_t)((b * 32 + kcb) * NPTS + mbase + m_l)) * 16;
      __builtin_amdgcn_global_load_lds((global_cvoid*)srcp,
                                       (lds_void*)(sB + (r * 4096 + wv * 1024)),
                                       16, 0, 0);
    }
    asm volatile("s_waitcnt vmcnt(0)" ::: "memory");
    __syncthreads();

    f32x4 acc[4];
    #pragma unroll
    for (int ms = 0; ms < 4; ++ms) acc[ms] = (f32x4){0.f, 0.f, 0.f, 0.f};

    #pragma unroll
    for (int kk = 0; kk < 8; ++kk) {
      half8 bf[4];
      #pragma unroll
      for (int ms = 0; ms < 4; ++ms) {
        const unsigned row = ms * 16 + (l & 15);
        const unsigned addr =
            (row * 512 + kk * 64 + ((l >> 4) & 3) * 16) ^ ((row & 7) << 4);
        bf[ms] = *reinterpret_cast<const half8*>(sB + addr);
      }
      #pragma unroll
      for (int ms = 0; ms < 4; ++ms)
        acc[ms] = __builtin_amdgcn_mfma_f32_16x16x32_f16(af[kk], bf[ms], acc[ms], 0, 0, 0);
    }

    // epilogue: candidate = b2pc[m] - 2*ab ; running min over m
    #pragma unroll
    for (int ms = 0; ms < 4; ++ms) {
      const float bp = b2pc[b * NPTS + mbase + ms * 16 + (l & 15)];
      #pragma unroll
      for (int r = 0; r < 4; ++r) {
        float cand = fmaf(-2.0f, acc[ms][r], bp);
        rmin[ms][r] = fminf(rmin[ms][r], cand);
      }
    }
    __syncthreads();   // tile fully consumed before next stage overwrites sB
  }

  // reduce over ms and over the 16 lanes (col groups), add a2p, write per-half min
  #pragma unroll
  for (int r = 0; r < 4; ++r) {
    float v = fminf(fminf(rmin[0][r], rmin[1][r]), fminf(rmin[2][r], rmin[3][r]));
    #pragma unroll
    for (int off = 1; off < 16; off <<= 1) v = fminf(v, __shfl_xor(v, off, 64));
    if ((l & 15) == 0) {
      const int n = rowg + r;
      d2part[(b * NPTS + n) * 2 + mh] = v + a2pr[r];
    }
  }
}

// ---------------------------------------------------------------- finalize
__global__ __launch_bounds__(256) void gm_finalize(
    const float* __restrict__ d2part, float* __restrict__ out)
{
  const int id = blockIdx.x * 256 + threadIdx.x;      // 0..16383  (b*4096 + n)
  const float d2 = fminf(d2part[id * 2], d2part[id * 2 + 1]);
  const float l2 = sqrtf(fmaxf(d2, 0.0f));
  const float s  = 2.0f / (1.0f + expf(l2));          // 2*sigmoid(-l2)
  const int b = id >> 12;
  const int n = id & 4095;
  const int h = n >> 6, w = n & 63;
  float4 v = make_float4(s, s, s, s);
  float* obase = out + ((size_t)(b * 256 + h * 4)) * 256 + w * 4;
  #pragma unroll
  for (int i = 0; i < 4; ++i)
    *reinterpret_cast<float4*>(obase + (size_t)i * 256) = v;
}

__global__ void gm_sentinel(float* out) { out[0] = 1.0e6f; }

extern "C" void kernel_launch(void* const* d_in, const int* in_sizes, int n_in,
                              void* d_out, int out_size, void* d_ws, size_t ws_size,
                              hipStream_t stream) {
  const float* a = (const float*)d_in[0];
  const float* b = (const float*)d_in[1];
  float* out = (float*)d_out;
  unsigned char* ws = (unsigned char*)d_ws;

  if (ws_size < (size_t)WS_TOTAL) {
    // unambiguous failure signal (absmax ~1e6) instead of OOB writes
    gm_sentinel<<<1, 1, 0, stream>>>(out);
    return;
  }

  gm_gather<<<dim3(64, 4, 2), 256, 0, stream>>>(a, b, ws);
  gm_gemm_min<<<dim3(2, 64, 4), 256, 0, stream>>>(
      ws + AC_OFF, ws + BC_OFF,
      (const float*)(ws + A2_OFF), (const float*)(ws + B2_OFF),
      (float*)(ws + DP_OFF));
  gm_finalize<<<64, 256, 0, stream>>>((const float*)(ws + DP_OFF), out);
}

// Round 2
// 69.105 us; speedup vs baseline: 1.5514x; 1.5514x over previous
//
#include <hip/hip_runtime.h>
#include <math.h>

// GlobalMatch: subsample stride-4 -> per batch 4096 pts x 256 ch,
// all-pairs min distance (a vs b), score = 2*sigmoid(-sqrt(d2min)), 4x4 upsample.
//
// Pipeline: gather/compact(fp16, K-chunked layout) -> fp16 MFMA GEMM with fused
// min-reduction (dbuf + counted vmcnt) -> finalize(score + upsample).

#define BATCH 4
#define CH    256
#define HH    256
#define WW    256
#define NPTS  4096          // 64*64 subsampled points per batch
#define EPSV  1e-6f

typedef _Float16 half8 __attribute__((ext_vector_type(8)));
typedef float    f32x4 __attribute__((ext_vector_type(4)));

typedef __attribute__((address_space(1))) const void global_cvoid;
typedef __attribute__((address_space(3))) void lds_void;

// ws layout (bytes)
#define AC_OFF   0u                           // fp16 chunks [b][kc(32)][n(4096)] * 16B = 8MB
#define BC_OFF   (8u << 20)                   // same, 8MB
#define A2_OFF   (16u << 20)                  // f32 [b][n]  a2 + 2eps*sa            (64KB)
#define B2_OFF   ((16u << 20) + (64u << 10))  // f32 [b][n]  b2 - 2eps*sb + C*eps^2  (64KB)
#define DP_OFF   ((16u << 20) + (128u << 10)) // f32 [b][n][4] per-quarter min d2    (256KB)
#define WS_TOTAL ((16u << 20) + (384u << 10))

// ---------------------------------------------------------------- gather
// grid (64 h, 4 b, 2 input), block 256.
__global__ __launch_bounds__(256) void gm_gather(
    const float* __restrict__ srcA, const float* __restrict__ srcB,
    unsigned char* __restrict__ ws)
{
  const int t  = threadIdx.x;
  const int h  = blockIdx.x;
  const int b  = blockIdx.y;
  const int z  = blockIdx.z;               // 0 -> a, 1 -> b
  const int w  = t & 63;
  const int wv = t >> 6;

  const float* src = z ? srcB : srcA;
  unsigned char* dst = ws + (z ? BC_OFF : AC_OFF);
  float* norms = (float*)(ws + (z ? B2_OFF : A2_OFF));
  const float epsSign = z ? -2.0f * EPSV : 2.0f * EPSV;
  const float addC    = z ? (float)CH * EPSV * EPSV : 0.0f;

  const float* rowbase = src + ((size_t)b * CH) * (HH * WW)
                             + (size_t)(h * 4) * WW + (size_t)(w * 4);
  float ssum = 0.0f, ssq = 0.0f;
  #pragma unroll
  for (int i = 0; i < 8; ++i) {
    const int kc = wv * 8 + i;             // 16B chunk index (8 channels)
    half8 hv;
    #pragma unroll
    for (int j = 0; j < 8; ++j) {
      const int c = kc * 8 + j;
      float v = rowbase[(size_t)c * (HH * WW)];
      ssum += v;
      ssq  = fmaf(v, v, ssq);
      hv[j] = (_Float16)v;
    }
    *reinterpret_cast<half8*>(dst + ((size_t)((b * 32 + kc) * NPTS + h * 64 + w)) * 16) = hv;
  }

  __shared__ float red[2][4][64];
  red[0][wv][w] = ssum;
  red[1][wv][w] = ssq;
  __syncthreads();
  if (t < 64) {
    float sm = red[0][0][t] + red[0][1][t] + red[0][2][t] + red[0][3][t];
    float sq = red[1][0][t] + red[1][1][t] + red[1][2][t] + red[1][3][t];
    norms[b * NPTS + h * 64 + t] = fmaf(epsSign, sm, sq) + addC;
  }
}

// ---------------------------------------------------------------- gemm + min
// grid 256 (1D, XCD-chunk swizzled), block 512 (8 waves).
// Block: 256 n rows x 1024 m cols, K=256 resident in registers for A.
// A staged through LDS in two 128-row halves -> af[2][8] per wave (wave owns 32 n).
// B streamed in 64-m tiles, double-buffered (2x32KB), counted vmcnt(4).
// XOR swizzle byte ^= ((row&7)<<4) on BOTH global_load_lds source and ds_read.
__device__ __forceinline__ void stage_b_tile(const unsigned char* __restrict__ Bc,
                                             int b, int mbase,
                                             unsigned char* dst, int t, int wv) {
  #pragma unroll
  for (int r = 0; r < 4; ++r) {
    unsigned x  = (unsigned)(r * 512 + t) * 16;            // linear dest byte in 32KB
    unsigned lb = x ^ (((x >> 9) & 7) << 4);               // logical byte
    unsigned m_l = lb >> 9;                                // 0..63
    unsigned kcb = (lb & 511) >> 4;                        // 0..31
    const unsigned char* srcp =
        Bc + ((size_t)((b * 32 + kcb) * NPTS + mbase + m_l)) * 16;
    __builtin_amdgcn_global_load_lds((global_cvoid*)srcp,
                                     (lds_void*)(dst + (r * 8192 + wv * 1024)),
                                     16, 0, 0);
  }
}

__global__ __launch_bounds__(512, 2) void gm_gemm_min(
    const unsigned char* __restrict__ Ac, const unsigned char* __restrict__ Bc,
    const float* __restrict__ a2p, const float* __restrict__ b2pc,
    float* __restrict__ d2part)
{
  __shared__ __align__(16) unsigned char smem[65536];

  const int t  = threadIdx.x;
  const int l  = t & 63;
  const int wv = t >> 6;                   // 0..7
  const int q  = (l >> 4) & 3;

  // bijective XCD-chunk swizzle (256 blocks, 8 XCDs, 32 per chunk)
  const int orig    = blockIdx.x;
  const int logical = (orig & 7) * 32 + (orig >> 3);
  const int ns = logical & 15;             // 16 n-strips
  const int mq = (logical >> 4) & 3;       // 4 m-quarters
  const int b  = logical >> 6;             // 4 batches
  const int nbase  = ns * 256;
  const int mstart = mq * 1024;

  // ---- stage A (two 128-row halves through smem) and read fragments
  half8 af[2][8];
  #pragma unroll
  for (int half = 0; half < 2; ++half) {
    #pragma unroll
    for (int r = 0; r < 8; ++r) {
      unsigned x  = (unsigned)(r * 512 + t) * 16;          // 0..64KB
      unsigned lb = x ^ (((x >> 9) & 7) << 4);
      unsigned n_l = lb >> 9;                              // 0..127
      unsigned kcb = (lb & 511) >> 4;
      const unsigned char* srcp =
          Ac + ((size_t)((b * 32 + kcb) * NPTS + nbase + half * 128 + n_l)) * 16;
      __builtin_amdgcn_global_load_lds((global_cvoid*)srcp,
                                       (lds_void*)(smem + (r * 8192 + wv * 1024)),
                                       16, 0, 0);
    }
    asm volatile("s_waitcnt vmcnt(0)" ::: "memory");
    __builtin_amdgcn_s_barrier();
    if ((wv >> 2) == half) {               // waves 0-3 in half0, 4-7 in half1
      #pragma unroll
      for (int nf = 0; nf < 2; ++nf) {
        const unsigned rr   = (wv & 3) * 32 + nf * 16 + (l & 15);  // lds row 0..127
        const unsigned base = rr * 512 + q * 16;
        const unsigned sw   = (rr & 7) << 4;
        #pragma unroll
        for (int kk = 0; kk < 8; ++kk)
          af[nf][kk] = *reinterpret_cast<const half8*>(smem + ((base + kk * 64) ^ sw));
      }
    }
    asm volatile("s_waitcnt lgkmcnt(0)" ::: "memory");
    __builtin_amdgcn_s_barrier();
  }

  float rmin[2][4];
  #pragma unroll
  for (int nf = 0; nf < 2; ++nf)
    #pragma unroll
    for (int r = 0; r < 4; ++r) rmin[nf][r] = 3.0e38f;

  // ---- main loop: 16 B-tiles of 64 m, double-buffered, counted vmcnt
  stage_b_tile(Bc, b, mstart, smem, t, wv);                // tile 0 -> buf0
  for (int mt = 0; mt < 16; ++mt) {
    unsigned char* cb = (mt & 1) ? smem + 32768 : smem;    // compute buffer
    unsigned char* nb = (mt & 1) ? smem : smem + 32768;    // prefetch buffer
    if (mt < 15) {
      stage_b_tile(Bc, b, mstart + (mt + 1) * 64, nb, t, wv);
      asm volatile("s_waitcnt vmcnt(4)" ::: "memory");     // tile mt landed; mt+1 in flight
    } else {
      asm volatile("s_waitcnt vmcnt(0)" ::: "memory");
    }
    __builtin_amdgcn_s_barrier();

    f32x4 acc[2][4];
    #pragma unroll
    for (int nf = 0; nf < 2; ++nf)
      #pragma unroll
      for (int ms = 0; ms < 4; ++ms) acc[nf][ms] = (f32x4){0.f, 0.f, 0.f, 0.f};

    #pragma unroll
    for (int kk = 0; kk < 8; ++kk) {
      half8 bf[4];
      #pragma unroll
      for (int ms = 0; ms < 4; ++ms) {
        const unsigned rr   = ms * 16 + (l & 15);
        const unsigned addr = (rr * 512 + kk * 64 + q * 16) ^ ((rr & 7) << 4);
        bf[ms] = *reinterpret_cast<const half8*>(cb + addr);
      }
      #pragma unroll
      for (int ms = 0; ms < 4; ++ms) {
        acc[0][ms] = __builtin_amdgcn_mfma_f32_16x16x32_f16(af[0][kk], bf[ms], acc[0][ms], 0, 0, 0);
        acc[1][ms] = __builtin_amdgcn_mfma_f32_16x16x32_f16(af[1][kk], bf[ms], acc[1][ms], 0, 0, 0);
      }
    }

    const int mbase = mstart + mt * 64;
    #pragma unroll
    for (int ms = 0; ms < 4; ++ms) {
      const float bp = b2pc[b * NPTS + mbase + ms * 16 + (l & 15)];
      #pragma unroll
      for (int r = 0; r < 4; ++r) {
        rmin[0][r] = fminf(rmin[0][r], fmaf(-2.0f, acc[0][ms][r], bp));
        rmin[1][r] = fminf(rmin[1][r], fmaf(-2.0f, acc[1][ms][r], bp));
      }
    }
    __builtin_amdgcn_s_barrier();          // all reads of cb done before it is restaged
  }

  // ---- reduce over the 16 col-lanes, add a2 term, write per-quarter min
  #pragma unroll
  for (int nf = 0; nf < 2; ++nf)
    #pragma unroll
    for (int r = 0; r < 4; ++r) {
      float v = rmin[nf][r];
      v = fminf(v, __shfl_xor(v, 1, 64));
      v = fminf(v, __shfl_xor(v, 2, 64));
      v = fminf(v, __shfl_xor(v, 4, 64));
      v = fminf(v, __shfl_xor(v, 8, 64));
      if ((l & 15) == 0) {
        const int n = nbase + wv * 32 + nf * 16 + q * 4 + r;
        d2part[(size_t)(b * NPTS + n) * 4 + mq] = v + a2p[b * NPTS + n];
      }
    }
}

// ---------------------------------------------------------------- finalize
__global__ __launch_bounds__(256) void gm_finalize(
    const float* __restrict__ d2part, float* __restrict__ out)
{
  const int id = blockIdx.x * 256 + threadIdx.x;      // 0..16383  (b*4096 + n)
  const f32x4 v4 = *reinterpret_cast<const f32x4*>(d2part + (size_t)id * 4);
  const float d2 = fminf(fminf(v4[0], v4[1]), fminf(v4[2], v4[3]));
  const float l2 = sqrtf(fmaxf(d2, 0.0f));
  const float s  = 2.0f / (1.0f + expf(l2));          // 2*sigmoid(-l2)
  const int b = id >> 12;
  const int n = id & 4095;
  const int h = n >> 6, w = n & 63;
  float4 v = make_float4(s, s, s, s);
  float* obase = out + ((size_t)(b * 256 + h * 4)) * 256 + w * 4;
  #pragma unroll
  for (int i = 0; i < 4; ++i)
    *reinterpret_cast<float4*>(obase + (size_t)i * 256) = v;
}

__global__ void gm_sentinel(float* out) { out[0] = 1.0e6f; }

extern "C" void kernel_launch(void* const* d_in, const int* in_sizes, int n_in,
                              void* d_out, int out_size, void* d_ws, size_t ws_size,
                              hipStream_t stream) {
  const float* a = (const float*)d_in[0];
  const float* b = (const float*)d_in[1];
  float* out = (float*)d_out;
  unsigned char* ws = (unsigned char*)d_ws;

  if (ws_size < (size_t)WS_TOTAL) {
    gm_sentinel<<<1, 1, 0, stream>>>(out);
    return;
  }

  gm_gather<<<dim3(64, 4, 2), 256, 0, stream>>>(a, b, ws);
  gm_gemm_min<<<256, 512, 0, stream>>>(
      ws + AC_OFF, ws + BC_OFF,
      (const float*)(ws + A2_OFF), (const float*)(ws + B2_OFF),
      (float*)(ws + DP_OFF));
  gm_finalize<<<64, 256, 0, stream>>>((const float*)(ws + DP_OFF), out);
}